// Round 1
// baseline (59.935 us; speedup 1.0000x reference)
//
#include <hip/hip_runtime.h>

// PPScatter: out[b, :, y, x] = x[b, :, p] for pillars with flag==1,
// last-write-wins on duplicate (y,x) per batch (NumPy semantics -> max p wins).
//
// Inputs (setup_inputs order):
//   d_in[0]: x    float32 [B=4, C=64, P=12000]
//   d_in[1]: inds int32   [B, P, 3] = (flag, xi, yi)
// Output: float32 [B, C, H=512, W=512]
//
// Strategy: 2-pass winner-index scatter + full-canvas coalesced gather.
//   pass 0: memset winner[B*H*W] = -1 (d_ws)
//   pass 1: atomicMax(winner[b,y,x], p) for flagged pillars  (48k cheap atomics)
//   pass 2: every output element written exactly once, coalesced float4:
//           out[b,c,y,x] = win>=0 ? x[b,c,win] : 0
// This fuses the 268MB zero-init with the scatter into one streaming write.

#define B_ 4
#define C_ 64
#define P_ 12000
#define H_ 512
#define W_ 512
#define HW_ (H_ * W_)          // 262144 = 1<<18

__global__ void pp_winner_kernel(const int* __restrict__ inds,
                                 int* __restrict__ win) {
    int i = blockIdx.x * blockDim.x + threadIdx.x;   // i in [0, B*P)
    if (i >= B_ * P_) return;
    int b = i / P_;
    int p = i - b * P_;
    int flag = inds[i * 3 + 0];
    if (flag == 1) {
        int xi = inds[i * 3 + 1];
        int yi = inds[i * 3 + 2];
        // mode='drop' semantics: out-of-range indices are dropped
        if ((unsigned)xi < (unsigned)W_ && (unsigned)yi < (unsigned)H_) {
            atomicMax(&win[(b * H_ + yi) * W_ + xi], p);
        }
    }
}

// Block = 256 threads, each thread owns 4 consecutive cells (x-direction),
// loops over all 64 channels. Stores are float4, fully coalesced.
// Grid = B*HW/1024 = 1024 blocks (blocks never straddle a batch: HW%1024==0).
__global__ __launch_bounds__(256) void pp_gather_kernel(
        const float* __restrict__ x,
        const int* __restrict__ win,
        float* __restrict__ out) {
    const int t = threadIdx.x;
    const long cellIdx = (long)blockIdx.x * 1024 + (long)t * 4;
    const int b    = (int)(cellIdx >> 18);        // / HW_
    const int cell = (int)(cellIdx & (HW_ - 1));  // % HW_

    const int4 w4 = *reinterpret_cast<const int4*>(win + ((size_t)b << 18) + cell);

    const float* xb = x + (size_t)b * (C_ * P_);
    float* ob = out + (((size_t)b * C_) << 18) + cell;

    #pragma unroll 4
    for (int c = 0; c < C_; ++c) {
        const float* xc = xb + (size_t)c * P_;
        float4 v;
        v.x = (w4.x >= 0) ? xc[w4.x] : 0.0f;   // predicated gathers: masked
        v.y = (w4.y >= 0) ? xc[w4.y] : 0.0f;   // lanes issue no transactions
        v.z = (w4.z >= 0) ? xc[w4.z] : 0.0f;
        v.w = (w4.w >= 0) ? xc[w4.w] : 0.0f;
        *reinterpret_cast<float4*>(ob + ((size_t)c << 18)) = v;
    }
}

extern "C" void kernel_launch(void* const* d_in, const int* in_sizes, int n_in,
                              void* d_out, int out_size, void* d_ws, size_t ws_size,
                              hipStream_t stream) {
    const float* x   = (const float*)d_in[0];
    const int* inds  = (const int*)d_in[1];
    float* out       = (float*)d_out;
    int* win         = (int*)d_ws;            // B*H*W ints = 4 MB

    // winner = -1 everywhere (0xFF bytes == -1 as int32)
    hipMemsetAsync(win, 0xFF, (size_t)B_ * HW_ * sizeof(int), stream);

    const int nPillars = B_ * P_;
    pp_winner_kernel<<<(nPillars + 255) / 256, 256, 0, stream>>>(inds, win);

    const int nBlocks = (B_ * HW_) / 1024;    // 1024 blocks of 256 threads
    pp_gather_kernel<<<nBlocks, 256, 0, stream>>>(x, win, out);
}